// Round 7
// baseline (428.076 us; speedup 1.0000x reference)
//
#include <hip/hip_runtime.h>
#include <stdint.h>

#define DIM 128
#define LN_EPS 1e-5f
#define ELLK 64
#define ATS 264   // a_tile row stride in bf16 elems (528B = 33*16B, bank-friendly)

typedef __attribute__((ext_vector_type(8))) short bf16x8;
typedef __attribute__((ext_vector_type(4))) float f32x4;

static __device__ __forceinline__ uint16_t f2bf(float f) {
    uint32_t u = __float_as_uint(f);
    return (uint16_t)((u + 0x7fffu + ((u >> 16) & 1u)) >> 16);
}

// ---------------------------------------------------------------------------
// K1: ELL build (deg + slot via one atomic; overflow pairs for deg>64, which
// is empty for Poisson(12) degrees but kept for correctness) + fp32->bf16
// conversion of Wc = [Wl | Wr]  (Wc[d][k], k<128 -> Wl[d][k], else Wr).
// Replaces R6's degree/scan1/scan2/fill (scan only existed to make CSR offs;
// ELL needs none).
// ---------------------------------------------------------------------------
__global__ __launch_bounds__(256) void prep_kernel(
    const int* __restrict__ ei,
    const float* __restrict__ Wl,
    const float* __restrict__ Wr,
    int* __restrict__ deg, int* __restrict__ novf,
    int* __restrict__ ell, int* __restrict__ ovf,
    uint16_t* __restrict__ wc, int E)
{
    int tid = blockIdx.x * blockDim.x + threadIdx.x;
    int nth = gridDim.x * blockDim.x;
    for (int e = tid; e < E; e += nth) {
        int src = ei[e];
        int dst = ei[E + e];
        int r = atomicAdd(deg + dst, 1);
        if (r < ELLK) {
            ell[dst * ELLK + r] = src;
        } else {
            int p = atomicAdd(novf, 1);
            ovf[2 * p] = dst;
            ovf[2 * p + 1] = src;
        }
    }
    for (int i = tid; i < DIM * 256; i += nth) {
        int d = i >> 8, k = i & 255;
        float v = (k < DIM) ? Wl[d * DIM + k] : Wr[d * DIM + (k - DIM)];
        wc[i] = f2bf(v);
    }
}

// ---------------------------------------------------------------------------
// K2: fused ELL-gather-mean ; h = [mean|x] @ Wc^T + bl (MFMA bf16) ;
// LayerNorm ; ReLU.  One wave per 16 rows (16x16 MFMA tiles, N%16==0).
// Gather: lane owns features {lane, lane+64}; 32 loads in flight across 16
// rows. LDS transpose (stride ATS) into A-frag layout A[m=lane&15][k=quad*8+j].
// Wc bf16 B-frags streamed from global (L1-resident, shared by all waves).
// C/D layout: col=lane&15, row=quad*4+reg (verified m89/m91).
// ---------------------------------------------------------------------------
__global__ __launch_bounds__(256) void fused_kernel(
    const float* __restrict__ x,
    const int* __restrict__ deg,
    const int* __restrict__ ell,
    const int* __restrict__ novf,
    const int* __restrict__ ovf,
    const uint16_t* __restrict__ wc,
    const float* __restrict__ bl,
    const float* __restrict__ gma,
    const float* __restrict__ bta,
    float* __restrict__ out,
    int N)
{
    __shared__ uint16_t atile_s[4][16 * ATS];
    const int lane = threadIdx.x & 63;
    const int wib  = threadIdx.x >> 6;
    const int wave = blockIdx.x * 4 + wib;
    const int row0 = wave * 16;
    if (row0 >= N) return;

    // ---- per-row scalar degree
    int dg_s[16];
    #pragma unroll
    for (int r = 0; r < 16; ++r) {
        int row = row0 + r;
        dg_s[r] = (row < N) ? __builtin_amdgcn_readfirstlane(deg[row]) : 0;
    }

    int nell[16], mx = 0;
    #pragma unroll
    for (int r = 0; r < 16; ++r) {
        int t = dg_s[r] < ELLK ? dg_s[r] : ELLK;
        nell[r] = t;
        mx = (t > mx) ? t : mx;
    }

    // ---- ELL gather: 16 rows interleaved, single <=64 chunk
    int sidx[16];
    #pragma unroll
    for (int r = 0; r < 16; ++r)
        sidx[r] = (lane < nell[r]) ? ell[(size_t)(row0 + r) * ELLK + lane] : 0;

    float m0[16], m1[16];
    #pragma unroll
    for (int r = 0; r < 16; ++r) { m0[r] = 0.0f; m1[r] = 0.0f; }

    for (int j = 0; j < mx; ++j) {
        #pragma unroll
        for (int r = 0; r < 16; ++r) {
            float p = (j < nell[r]) ? 1.0f : 0.0f;   // wave-uniform
            int s = __builtin_amdgcn_readlane(sidx[r], j);
            const float* xr = x + (size_t)s * DIM;
            m0[r] = fmaf(p, xr[lane], m0[r]);
            m1[r] = fmaf(p, xr[lane + 64], m1[r]);
        }
    }

    // ---- overflow edges (deg > 64): empty in practice, correct always
    int no = __builtin_amdgcn_readfirstlane(novf[0]);
    for (int i = 0; i < no; ++i) {
        int dsto = __builtin_amdgcn_readfirstlane(ovf[2 * i]);
        int srco = __builtin_amdgcn_readfirstlane(ovf[2 * i + 1]);
        const float* xr = x + (size_t)srco * DIM;
        float v0 = xr[lane], v1 = xr[lane + 64];
        #pragma unroll
        for (int r = 0; r < 16; ++r) {
            float p = (dsto == row0 + r) ? 1.0f : 0.0f;
            m0[r] = fmaf(p, v0, m0[r]);
            m1[r] = fmaf(p, v1, m1[r]);
        }
    }

    // ---- write a = [mean | x] as bf16 into LDS (per-wave region, no barrier)
    uint16_t* at = atile_s[wib];
    #pragma unroll
    for (int r = 0; r < 16; ++r) {
        int row = row0 + r;
        int rr = (row < N) ? row : 0;
        float rc = (dg_s[r] > 0) ? (1.0f / (float)dg_s[r]) : 0.0f;
        const float* xw = x + (size_t)rr * DIM;
        at[r * ATS + lane]       = f2bf(m0[r] * rc);
        at[r * ATS + lane + 64]  = f2bf(m1[r] * rc);
        at[r * ATS + 128 + lane] = f2bf(xw[lane]);
        at[r * ATS + 192 + lane] = f2bf(xw[lane + 64]);
    }

    // ---- MFMA: h(16x128) = a(16x256) @ Wc^T, k-chunks of 32
    const int nsub = lane & 15;
    const int quad = lane >> 4;

    f32x4 acc[8];
    #pragma unroll
    for (int t = 0; t < 8; ++t) {
        float b = bl[t * 16 + nsub];
        acc[t] = (f32x4){b, b, b, b};
    }

    #pragma unroll
    for (int c = 0; c < 8; ++c) {
        bf16x8 af = *(const bf16x8*)&at[nsub * ATS + c * 32 + quad * 8];
        #pragma unroll
        for (int t = 0; t < 8; ++t) {
            bf16x8 bfr = *(const bf16x8*)&wc[(size_t)(t * 16 + nsub) * 256 + c * 32 + quad * 8];
            acc[t] = __builtin_amdgcn_mfma_f32_16x16x32_bf16(af, bfr, acc[t], 0, 0, 0);
        }
    }

    // ---- LayerNorm + ReLU + store. Row r=quad*4+i lives in quad's 16 lanes.
    float g[8], be[8];
    #pragma unroll
    for (int t = 0; t < 8; ++t) {
        g[t]  = gma[t * 16 + nsub];
        be[t] = bta[t * 16 + nsub];
    }

    #pragma unroll
    for (int i = 0; i < 4; ++i) {
        float s = 0.0f, q = 0.0f;
        #pragma unroll
        for (int t = 0; t < 8; ++t) {
            float v = acc[t][i];
            s += v;
            q += v * v;
        }
        #pragma unroll
        for (int off = 1; off < 16; off <<= 1) {   // reduce within 16-lane quad
            s += __shfl_xor(s, off, 64);
            q += __shfl_xor(q, off, 64);
        }
        float mu = s * (1.0f / 128.0f);
        float var = q * (1.0f / 128.0f) - mu * mu;
        float rs = rsqrtf(fmaxf(var, 0.0f) + LN_EPS);

        int grow = row0 + quad * 4 + i;
        if (grow < N) {
            float* op = out + (size_t)grow * DIM;
            #pragma unroll
            for (int t = 0; t < 8; ++t) {
                float o = fmaxf((acc[t][i] - mu) * rs * g[t] + be[t], 0.0f);
                op[t * 16 + nsub] = o;
            }
        }
    }
}

extern "C" void kernel_launch(void* const* d_in, const int* in_sizes, int n_in,
                              void* d_out, int out_size, void* d_ws, size_t ws_size,
                              hipStream_t stream) {
    const float* x  = (const float*)d_in[0];
    const int* ei   = (const int*)d_in[1];
    const float* Wl = (const float*)d_in[2];
    const float* bl = (const float*)d_in[3];
    const float* Wr = (const float*)d_in[4];
    const float* ga = (const float*)d_in[5];
    const float* be = (const float*)d_in[6];
    float* out = (float*)d_out;

    int N = in_sizes[0] / DIM;   // 50000
    int E = in_sizes[1] / 2;     // 600000

    // ws layout (ints unless noted): deg[N] | novf[16] | wc[32768 u16] |
    // ell[N*64] | ovf[2E]
    int* deg      = (int*)d_ws;
    int* novf     = deg + N;
    uint16_t* wc  = (uint16_t*)(novf + 16);
    int* ell      = (int*)(wc + DIM * 256);
    int* ovf      = ell + (size_t)N * ELLK;

    hipMemsetAsync(deg, 0, (size_t)(N + 16) * sizeof(int), stream);

    prep_kernel<<<(E + 255) / 256, 256, 0, stream>>>(
        ei, Wl, Wr, deg, novf, ell, ovf, wc, E);

    {
        int waves = (N + 15) / 16;            // 3125
        int blocks = (waves + 3) / 4;         // 782
        fused_kernel<<<blocks, 256, 0, stream>>>(
            x, deg, ell, novf, ovf, wc, bl, ga, be, out, N);
    }
}

// Round 8
// 198.715 us; speedup vs baseline: 2.1542x; 2.1542x over previous
//
#include <hip/hip_runtime.h>
#include <stdint.h>

#define DIM 128
#define LN_EPS 1e-5f
#define ELLK 64
#define ATS 264   // LDS A-tile row stride in bf16 elems (528B, 16B-aligned rows)
#define DEGS 16   // deg stride in ints: one counter per 64B line (atomic anti-ping-pong)

typedef __attribute__((ext_vector_type(8))) short bf16x8;
typedef __attribute__((ext_vector_type(4))) float f32x4;

static __device__ __forceinline__ uint16_t f2bf(float f) {
    uint32_t u = __float_as_uint(f);
    return (uint16_t)((u + 0x7fffu + ((u >> 16) & 1u)) >> 16);
}

// ---------------------------------------------------------------------------
// K1: ELL build + bf16 weight concat Wc = [Wl | Wr].
// deg padded to 1 counter / 64B line: 600k atomics over 50k *lines* instead of
// 3125 lines (R7: ~192 same-line device-scope atomics/line serialized ~90us).
// ---------------------------------------------------------------------------
__global__ __launch_bounds__(256) void prep_kernel(
    const int* __restrict__ ei,
    const float* __restrict__ Wl,
    const float* __restrict__ Wr,
    int* __restrict__ degp, int* __restrict__ novf,
    int* __restrict__ ell, int* __restrict__ ovf,
    uint16_t* __restrict__ wc, int E)
{
    int tid = blockIdx.x * blockDim.x + threadIdx.x;
    int nth = gridDim.x * blockDim.x;
    for (int e = tid; e < E; e += nth) {
        int src = ei[e];
        int dst = ei[E + e];
        int r = atomicAdd(degp + (size_t)dst * DEGS, 1);
        if (r < ELLK) {
            ell[(size_t)dst * ELLK + r] = src;
        } else {
            int q = atomicAdd(novf, 1);
            ovf[2 * q] = dst;
            ovf[2 * q + 1] = src;
        }
    }
    for (int i = tid; i < DIM * 256; i += nth) {
        int d = i >> 8, k = i & 255;
        float v = (k < DIM) ? Wl[d * DIM + k] : Wr[d * DIM + (k - DIM)];
        wc[i] = f2bf(v);
    }
}

// ---------------------------------------------------------------------------
// K2: fused ELL-gather-mean ; h = [mean|x]@Wc^T + bl (MFMA) ; LN ; ReLU.
// Block = 4 waves = 2 tiles of 16 rows. Each tile is built by TWO waves
// (8 gather rows each — restores R6's proven 6250-wave / 16-loads-in-flight
// gather shape that R7's 16-row waves destroyed), then each wave computes
// half the output features (t = h*4..h*4+3, 32 MFMAs).
// A-frag A[m=lane&15][k=quad*8+j]; C/D col=lane&15,row=quad*4+reg (validated
// by R7's pass, absmax 0.031).
// ---------------------------------------------------------------------------
__global__ __launch_bounds__(256, 4) void fused_kernel(
    const float* __restrict__ x,
    const int* __restrict__ degp,
    const int* __restrict__ ell,
    const int* __restrict__ novf,
    const int* __restrict__ ovf,
    const uint16_t* __restrict__ wc,
    const float* __restrict__ bl,
    const float* __restrict__ gma,
    const float* __restrict__ bta,
    float* __restrict__ out,
    int N)
{
    __shared__ uint16_t atile[2][16 * ATS];
    __shared__ float pln[2][16][2][2];

    const int lane = threadIdx.x & 63;
    const int w    = threadIdx.x >> 6;
    const int p    = w >> 1;          // tile within block
    const int h    = w & 1;           // half (gather rows / output features)
    const int tile_row0 = blockIdx.x * 32 + p * 16;
    const int grow0     = tile_row0 + h * 8;   // this wave's 8 gather rows

    // ---- per-row degree (padded stride)
    int dg_s[8], nell[8], mx = 0;
    #pragma unroll
    for (int r = 0; r < 8; ++r) {
        int row = grow0 + r;
        dg_s[r] = (row < N) ? __builtin_amdgcn_readfirstlane(degp[(size_t)row * DEGS]) : 0;
        int t = dg_s[r] < ELLK ? dg_s[r] : ELLK;
        nell[r] = t;
        mx = (t > mx) ? t : mx;
    }

    // ---- ELL gather: 8 rows interleaved (16 loads in flight)
    int sidx[8];
    #pragma unroll
    for (int r = 0; r < 8; ++r)
        sidx[r] = (lane < nell[r]) ? ell[(size_t)(grow0 + r) * ELLK + lane] : 0;

    float m0[8], m1[8];
    #pragma unroll
    for (int r = 0; r < 8; ++r) { m0[r] = 0.0f; m1[r] = 0.0f; }

    for (int j = 0; j < mx; ++j) {
        #pragma unroll
        for (int r = 0; r < 8; ++r) {
            float pr = (j < nell[r]) ? 1.0f : 0.0f;   // wave-uniform
            int s = __builtin_amdgcn_readlane(sidx[r], j);
            const float* xr = x + (size_t)s * DIM;
            m0[r] = fmaf(pr, xr[lane], m0[r]);
            m1[r] = fmaf(pr, xr[lane + 64], m1[r]);
        }
    }

    // ---- overflow edges (deg > 64): empty for Poisson(12), correct always
    {
        int no = __builtin_amdgcn_readfirstlane(novf[0]);
        for (int i = 0; i < no; ++i) {
            int dsto = __builtin_amdgcn_readfirstlane(ovf[2 * i]);
            int srco = __builtin_amdgcn_readfirstlane(ovf[2 * i + 1]);
            if (dsto >= grow0 && dsto < grow0 + 8) {
                const float* xr = x + (size_t)srco * DIM;
                float v0 = xr[lane], v1 = xr[lane + 64];
                #pragma unroll
                for (int r = 0; r < 8; ++r) {
                    float pr = (dsto == grow0 + r) ? 1.0f : 0.0f;
                    m0[r] = fmaf(pr, v0, m0[r]);
                    m1[r] = fmaf(pr, v1, m1[r]);
                }
            }
        }
    }

    // ---- write a = [mean | x] rows h*8..h*8+7 of tile p as bf16
    {
        uint16_t* at = atile[p];
        #pragma unroll
        for (int r = 0; r < 8; ++r) {
            int row = grow0 + r;
            int rr = (row < N) ? row : 0;
            float rc = (dg_s[r] > 0) ? (1.0f / (float)dg_s[r]) : 0.0f;
            const float* xw = x + (size_t)rr * DIM;
            int lr = h * 8 + r;
            at[lr * ATS + lane]       = f2bf(m0[r] * rc);
            at[lr * ATS + 64 + lane]  = f2bf(m1[r] * rc);
            at[lr * ATS + 128 + lane] = f2bf(xw[lane]);
            at[lr * ATS + 192 + lane] = f2bf(xw[lane + 64]);
        }
    }
    __syncthreads();

    // ---- MFMA: this wave computes output features [h*64, h*64+64) of tile p
    const int nsub = lane & 15;
    const int quad = lane >> 4;
    const uint16_t* at = atile[p];

    f32x4 acc[4];
    #pragma unroll
    for (int tt = 0; tt < 4; ++tt) {
        float b = bl[(h * 4 + tt) * 16 + nsub];
        acc[tt] = (f32x4){b, b, b, b};
    }

    #pragma unroll
    for (int c = 0; c < 8; ++c) {
        bf16x8 af = *(const bf16x8*)&at[nsub * ATS + c * 32 + quad * 8];
        #pragma unroll
        for (int tt = 0; tt < 4; ++tt) {
            int tg = h * 4 + tt;
            bf16x8 bfr = *(const bf16x8*)&wc[(size_t)(tg * 16 + nsub) * 256 + c * 32 + quad * 8];
            acc[tt] = __builtin_amdgcn_mfma_f32_16x16x32_bf16(af, bfr, acc[tt], 0, 0, 0);
        }
    }

    // ---- LN partial sums (this wave covers 64 of 128 features per row)
    #pragma unroll
    for (int i = 0; i < 4; ++i) {
        float s = 0.0f, q = 0.0f;
        #pragma unroll
        for (int tt = 0; tt < 4; ++tt) {
            float v = acc[tt][i];
            s += v;
            q += v * v;
        }
        #pragma unroll
        for (int off = 1; off < 16; off <<= 1) {
            s += __shfl_xor(s, off, 64);
            q += __shfl_xor(q, off, 64);
        }
        if (nsub == 0) {
            pln[p][quad * 4 + i][h][0] = s;
            pln[p][quad * 4 + i][h][1] = q;
        }
    }
    __syncthreads();

    // ---- combine halves, normalize, ReLU, store
    #pragma unroll
    for (int i = 0; i < 4; ++i) {
        int lrow = quad * 4 + i;
        float s = pln[p][lrow][0][0] + pln[p][lrow][1][0];
        float q = pln[p][lrow][0][1] + pln[p][lrow][1][1];
        float mu = s * (1.0f / 128.0f);
        float var = q * (1.0f / 128.0f) - mu * mu;
        float rs = rsqrtf(fmaxf(var, 0.0f) + LN_EPS);
        int grow = tile_row0 + lrow;
        if (grow < N) {
            float* op = out + (size_t)grow * DIM;
            #pragma unroll
            for (int tt = 0; tt < 4; ++tt) {
                int f = (h * 4 + tt) * 16 + nsub;
                float o = fmaxf((acc[tt][i] - mu) * rs * gma[f] + bta[f], 0.0f);
                op[f] = o;
            }
        }
    }
}

extern "C" void kernel_launch(void* const* d_in, const int* in_sizes, int n_in,
                              void* d_out, int out_size, void* d_ws, size_t ws_size,
                              hipStream_t stream) {
    const float* x  = (const float*)d_in[0];
    const int* ei   = (const int*)d_in[1];
    const float* Wl = (const float*)d_in[2];
    const float* bl = (const float*)d_in[3];
    const float* Wr = (const float*)d_in[4];
    const float* ga = (const float*)d_in[5];
    const float* be = (const float*)d_in[6];
    float* out = (float*)d_out;

    int N = in_sizes[0] / DIM;   // 50000
    int E = in_sizes[1] / 2;     // 600000

    // ws: degp[N*16] | novf[16] | wc[32768 u16] | ell[N*64] | ovf[2E]
    int* degp     = (int*)d_ws;
    int* novf     = degp + (size_t)N * DEGS;
    uint16_t* wc  = (uint16_t*)(novf + 16);
    int* ell      = (int*)(wc + DIM * 256);
    int* ovf      = ell + (size_t)N * ELLK;

    hipMemsetAsync(degp, 0, ((size_t)N * DEGS + 16) * sizeof(int), stream);

    prep_kernel<<<(E + 255) / 256, 256, 0, stream>>>(
        ei, Wl, Wr, degp, novf, ell, ovf, wc, E);

    {
        int blocks = (N + 31) / 32;   // 1563
        fused_kernel<<<blocks, 256, 0, stream>>>(
            x, degp, ell, novf, ovf, wc, bl, ga, be, out, N);
    }
}